// Round 13
// baseline (369.605 us; speedup 1.0000x reference)
//
#include <hip/hip_runtime.h>
#include <hip/hip_bf16.h>
#include <stdint.h>

#define BN 8192
#define DK 1024
#define BK 64
#define NT (DK / BK)          // 16 K-tiles
#define LSMOOTH 0.1f
#define EPSF 1e-7f
#define LN2F 0.69314718055994531f

typedef __bf16 bf16x8 __attribute__((ext_vector_type(8)));
typedef float f32x4 __attribute__((ext_vector_type(4)));

__device__ __forceinline__ unsigned short f2bf(float f) {
  union { float f; uint32_t u; } v; v.f = f;
  uint32_t u = v.u;
  u += 0x7fffu + ((u >> 16) & 1u);   // round-to-nearest-even
  return (unsigned short)(u >> 16);
}

// ---------------- prep: f32 -> bf16 conversion + row squared norms ----------------
__global__ __launch_bounds__(256) void prep_kernel(
    const float* __restrict__ sign, const float* __restrict__ text,
    unsigned short* __restrict__ Abf, unsigned short* __restrict__ Bbf,
    float* __restrict__ xx, float* __restrict__ yy) {
  const int b = blockIdx.x;          // 0..2*BN-1
  const int row = b & (BN - 1);
  const bool isB = b >= BN;
  const float4* src = (const float4*)((isB ? text : sign) + (size_t)row * DK);
  ushort4* dst = (ushort4*)((isB ? Bbf : Abf) + (size_t)row * DK);
  const int t = threadIdx.x;         // 256 threads, 1 float4 each (DK/4 = 256)
  float4 v = src[t];
  ushort4 o;
  o.x = f2bf(v.x); o.y = f2bf(v.y); o.z = f2bf(v.z); o.w = f2bf(v.w);
  dst[t] = o;
  float ss = v.x * v.x + v.y * v.y + v.z * v.z + v.w * v.w;
  #pragma unroll
  for (int off = 32; off; off >>= 1) ss += __shfl_down(ss, off);
  __shared__ float red[4];
  if ((t & 63) == 0) red[t >> 6] = ss;
  __syncthreads();
  if (t == 0) (isB ? yy : xx)[row] = red[0] + red[1] + red[2] + red[3];
}

// ---------------- fused GEMM: 128x128, BK=64, A direct-to-register, B-only LDS --------
// 4 waves (2M x 2N), per-wave 64x64. A fragments load straight from global into a
// ping-pong register set (prefetched one tile ahead, kept in flight across the barrier
// by counted vmcnt(8) — A loads are issued AFTER the B-stage GLLs so vmcnt(8) drains B
// only). B uses the proven swizzled global_load_lds path. LDS traffic halves vs R12
// (96->48 KB per block-iter); LDS = 16 KB -> 3 blocks/CU.
__global__ __launch_bounds__(256, 3) void gemm_fused(
    const unsigned short* __restrict__ Abf, const unsigned short* __restrict__ Bbf,
    const float* __restrict__ xx, const float* __restrict__ yy,
    const float* __restrict__ p_log_tau, const float* __restrict__ p_margin,
    float* __restrict__ row_partial, float* __restrict__ accums) {
  __shared__ __align__(16) char lds[16384];    // B tile only: 128 rows x 128 B

  const int tid = threadIdx.x;
  const int wave = tid >> 6, lane = tid & 63;
  const int l15 = lane & 15, g4 = lane >> 4;
  const int waveM = wave >> 1, waveN = wave & 1;        // 2 x 2
  const int bx = blockIdx.x, by = blockIdx.y;
  const int blockRow = by * 128, blockCol = bx * 128;

  // B staging: per GLL 256 threads cover 32 rows x 128B; thread t -> row t>>3,
  // 16B-chunk (t&7) ^ (row&7) (pre-swizzled source; LDS written linearly by HW)
  const int srow = tid >> 3;                            // 0..31
  const int schunk = (tid & 7) ^ (srow & 7);            // involution
  const unsigned short* bSrc = Bbf + (size_t)(blockCol + srow) * DK + schunk * 8;
  const int ldst = wave * 1024;

#define GLL(gp, lp) __builtin_amdgcn_global_load_lds(                                   \
      (const __attribute__((address_space(1))) void*)(gp),                             \
      (__attribute__((address_space(3))) void*)(lp), 16, 0, 0)
#define STAGE_B(kt) do {                                                                \
    _Pragma("unroll")                                                                   \
    for (int c_ = 0; c_ < 4; ++c_)                                                      \
      GLL(bSrc + (kt) * BK + c_ * 32 * DK, lds + c_ * 4096 + ldst);                     \
  } while (0)
#define RD(off) (*(const bf16x8*)(lds + (off)))
#define LOAD_A(kt, R_) do {                                                             \
    _Pragma("unroll")                                                                   \
    for (int m_ = 0; m_ < 4; ++m_) {                                                    \
      (R_)[m_][0] = *(const bf16x8*)(aBase + m_ * 16 * DK + (kt) * BK + g4 * 8);        \
      (R_)[m_][1] = *(const bf16x8*)(aBase + m_ * 16 * DK + (kt) * BK + 32 + g4 * 8);   \
    } } while (0)

  // A base: this lane's row (no swizzle; direct global)
  const unsigned short* aBase = Abf + (size_t)(blockRow + waveM * 64 + l15) * DK;

  f32x4 acc[4][4];
  #pragma unroll
  for (int m = 0; m < 4; ++m)
    #pragma unroll
    for (int n = 0; n < 4; ++n)
      acc[m][n] = (f32x4){0.f, 0.f, 0.f, 0.f};

  // B frag reads: row stride 128B; k-half kk -> chunk kk*4+g4, XOR row&7 (== l15&7)
  const int s7 = l15 & 7;
  const int bRow = (waveN * 64 + l15) * 128;
  const int c0 = (g4 ^ s7) << 4;
  const int c1 = ((4 + g4) ^ s7) << 4;

  bf16x8 xa[4][2], ya[4][2];

  // prologue: stage B(0), then issue A(0) (A newer than B -> vmcnt(8) drains B only)
  STAGE_B(0);
  LOAD_A(0, xa);
  asm volatile("s_waitcnt vmcnt(8)" ::: "memory");
  __builtin_amdgcn_s_barrier();
  asm volatile("" ::: "memory");

#define TILE(t_, CUR_, NXT_) do {                                                       \
    bf16x8 bf[4][2];                                                                    \
    _Pragma("unroll")                                                                   \
    for (int n_ = 0; n_ < 4; ++n_) {                                                    \
      bf[n_][0] = RD(bRow + n_ * 2048 + c0);                                            \
      bf[n_][1] = RD(bRow + n_ * 2048 + c1);                                            \
    }                                                                                   \
    __builtin_amdgcn_s_setprio(1);                                                      \
    _Pragma("unroll")                                                                   \
    for (int m_ = 0; m_ < 4; ++m_)                                                      \
      _Pragma("unroll")                                                                 \
      for (int n_ = 0; n_ < 4; ++n_) {                                                  \
        acc[m_][n_] = __builtin_amdgcn_mfma_f32_16x16x32_bf16((CUR_)[m_][0], bf[n_][0], \
                                                              acc[m_][n_], 0, 0, 0);    \
        acc[m_][n_] = __builtin_amdgcn_mfma_f32_16x16x32_bf16((CUR_)[m_][1], bf[n_][1], \
                                                              acc[m_][n_], 0, 0, 0);    \
      }                                                                                 \
    __builtin_amdgcn_s_setprio(0);                                                      \
    __builtin_amdgcn_s_barrier();                                                       \
    asm volatile("" ::: "memory");                                                      \
    if ((t_) + 1 < NT) {                                                                \
      STAGE_B((t_) + 1);                                                                \
      LOAD_A((t_) + 1, NXT_);                                                           \
      asm volatile("s_waitcnt vmcnt(8)" ::: "memory");                                  \
      __builtin_amdgcn_s_barrier();                                                     \
      asm volatile("" ::: "memory");                                                    \
    }                                                                                   \
  } while (0)

  for (int t = 0; t < NT; t += 2) {
    TILE(t, xa, ya);          // compute A(t), prefetch A(t+1) -> ya
    TILE(t + 1, ya, xa);      // compute A(t+1), prefetch A(t+2) -> xa
  }
#undef TILE
#undef STAGE_B
#undef GLL
#undef RD
#undef LOAD_A

  // ---- fused epilogue: poincare dist via log2, exp-sums, dist sums ----
  const float lt = *p_log_tau;
  const float mg = *p_margin;
  const float marg = fmaxf(mg, 0.f);
  const float tau = 1.99f / (1.f + __expf(-lt)) + 0.01f;
  const float nl = -LN2F / tau;            // exp(L2*nl) == exp(-dist/tau)
  const float em = __expf(-marg);          // diagonal exp correction factor
  const bool diagblk = (bx == by);

  float yyj[4], rcpy[4]; int gj[4];
  #pragma unroll
  for (int n = 0; n < 4; ++n) {
    gj[n] = blockCol + waveN * 64 + n * 16 + l15;        // C/D col = lane&15
    yyj[n] = yy[gj[n]];
    rcpy[n] = __builtin_amdgcn_rcpf(1.f - yyj[n]);
  }

  float dL = 0.f, dDiagL = 0.f;            // dist sums in log2 units
  float* rsum = (float*)lds;               // reuse LDS: [128 rows][2 waveN] partials

  #pragma unroll
  for (int m = 0; m < 4; ++m) {
    #pragma unroll
    for (int r = 0; r < 4; ++r) {
      const int rloc = waveM * 64 + m * 16 + g4 * 4 + r;
      const int gi = blockRow + rloc;                    // C/D row
      const float xxi = xx[gi];
      const float p2 = 2.f * __builtin_amdgcn_rcpf(1.f - xxi);
      float e_acc = 0.f;
      #pragma unroll
      for (int n = 0; n < 4; ++n) {
        const float xy = acc[m][n][r];
        const float sq = fmaxf(xxi + yyj[n] - 2.f * xy, 0.f);
        const float tt = sq * (p2 * rcpy[n]);            // arg = 1 + tt
        const float s = __builtin_amdgcn_sqrtf(tt * (tt + 2.f));
        const float w = tt + 1.f + s;                    // arg + sqrt(arg^2-1)
        const float L2 = __log2f(fmaxf(w, 1.f + EPSF));  // dist = L2 * ln2
        float e = __expf(L2 * nl);
        dL += L2;
        if (diagblk && gi == gj[n]) { dDiagL += L2; e *= em; }
        e_acc += e;
      }
      e_acc += __shfl_xor(e_acc, 1);
      e_acc += __shfl_xor(e_acc, 2);
      e_acc += __shfl_xor(e_acc, 4);
      e_acc += __shfl_xor(e_acc, 8);
      if (l15 == 0) rsum[rloc * 2 + waveN] = e_acc;
    }
  }

  // block-level scalar reductions -> 2 atomics per wave (log2 units)
  #pragma unroll
  for (int off = 32; off; off >>= 1) {
    dL += __shfl_down(dL, off);
    dDiagL += __shfl_down(dDiagL, off);
  }
  if (lane == 0) {
    atomicAdd(&accums[0], dL);
    if (diagblk) atomicAdd(&accums[1], dDiagL);
  }

  __syncthreads();
  if (tid < 128) {
    const float rs = rsum[tid * 2 + 0] + rsum[tid * 2 + 1];
    row_partial[(size_t)bx * BN + blockRow + tid] = rs;
  }
}

// ---------------- logsum: per-row sum of 64 col-tile partials, log, block-reduce ------
__global__ __launch_bounds__(256) void logsum_kernel(
    const float* __restrict__ row_partial, float* __restrict__ accums) {
  const int row = blockIdx.x * 256 + threadIdx.x;       // 32 blocks x 256 = 8192 rows
  float s = 0.f;
  #pragma unroll
  for (int c = 0; c < 64; ++c) s += row_partial[(size_t)c * BN + row];
  float lsum = __logf(s);
  #pragma unroll
  for (int off = 32; off; off >>= 1) lsum += __shfl_down(lsum, off);
  __shared__ float red[4];
  if ((threadIdx.x & 63) == 0) red[threadIdx.x >> 6] = lsum;
  __syncthreads();
  if (threadIdx.x == 0)
    atomicAdd(&accums[2], red[0] + red[1] + red[2] + red[3]);
}

// ---------------- final: linear combination ----------------
__global__ void final_kernel(
    const float* __restrict__ accums,
    const float* __restrict__ p_log_tau, const float* __restrict__ p_margin,
    float* __restrict__ out) {
  const float lt = *p_log_tau;
  const float mg = *p_margin;
  const float marg = fmaxf(mg, 0.f);
  const float tau = 1.99f / (1.f + __expf(-lt)) + 0.01f;
  const float C = marg;
  const float d_tot = accums[0] * LN2F;
  const float d_diag = accums[1] * LN2F;
  const float bf = (float)BN;
  const float mean_lse = accums[2] / bf + C;
  const float sum_scores = -d_tot / tau + marg * (bf * bf - bf);  // margin term closed-form
  const float sum_diag_scores = -d_diag / tau;
  const float loss = mean_lse
                   - (1.f - LSMOOTH) * (sum_diag_scores / bf)
                   - LSMOOTH * (sum_scores / (bf * bf));
  out[0] = loss;
  out[1] = d_diag / bf;   // pos_dist
  out[2] = tau;
  out[3] = mg;            // maximum(margin, margin) == margin
}

extern "C" void kernel_launch(void* const* d_in, const int* in_sizes, int n_in,
                              void* d_out, int out_size, void* d_ws, size_t ws_size,
                              hipStream_t stream) {
  const float* sign = (const float*)d_in[0];
  const float* text = (const float*)d_in[1];
  const float* p_log_tau = (const float*)d_in[2];
  const float* p_margin = (const float*)d_in[3];
  float* out = (float*)d_out;

  char* ws = (char*)d_ws;
  unsigned short* Abf = (unsigned short*)ws;                         // 16 MiB
  unsigned short* Bbf = (unsigned short*)(ws + (size_t)BN * DK * 2); // 16 MiB
  float* xx = (float*)(ws + (size_t)BN * DK * 4);
  float* yy = xx + BN;
  float* row_partial = yy + BN;                                      // 64 x 8192 floats
  float* accums = row_partial + 64 * BN;                             // 3 floats

  (void)hipMemsetAsync(accums, 0, 3 * sizeof(float), stream);
  prep_kernel<<<dim3(2 * BN), 256, 0, stream>>>(sign, text, Abf, Bbf, xx, yy);
  gemm_fused<<<dim3(BN / 128, BN / 128), 256, 0, stream>>>(
      Abf, Bbf, xx, yy, p_log_tau, p_margin, row_partial, accums);
  logsum_kernel<<<dim3(BN / 256), 256, 0, stream>>>(row_partial, accums);
  final_kernel<<<1, 1, 0, stream>>>(accums, p_log_tau, p_margin, out);
}

// Round 14
// 238.396 us; speedup vs baseline: 1.5504x; 1.5504x over previous
//
#include <hip/hip_runtime.h>
#include <hip/hip_bf16.h>
#include <stdint.h>

#define BN 8192
#define DK 1024
#define BKT 64                // K elements (= bytes) per tile
#define NKT (DK / BKT)        // 16 K-tiles
#define LSMOOTH 0.1f
#define EPSF 1e-7f
#define LN2F 0.69314718055994531f

typedef float f32x4 __attribute__((ext_vector_type(4)));

// ---------------- prep: f32 -> e4m3 (x16 pre-scale) + row squared norms ----------------
__global__ __launch_bounds__(256) void prep_kernel(
    const float* __restrict__ sign, const float* __restrict__ text,
    uint32_t* __restrict__ Afp, uint32_t* __restrict__ Bfp,
    float* __restrict__ xx, float* __restrict__ yy) {
  const int b = blockIdx.x;          // 0..2*BN-1
  const int row = b & (BN - 1);
  const bool isB = b >= BN;
  const float4* src = (const float4*)((isB ? text : sign) + (size_t)row * DK);
  uint32_t* dst = (isB ? Bfp : Afp) + (size_t)row * (DK / 4);
  const int t = threadIdx.x;         // 256 threads, 1 float4 each
  float4 v = src[t];
  uint32_t u = 0;
  u = __builtin_amdgcn_cvt_pk_fp8_f32(v.x * 16.f, v.y * 16.f, u, false);  // HW RNE e4m3
  u = __builtin_amdgcn_cvt_pk_fp8_f32(v.z * 16.f, v.w * 16.f, u, true);
  dst[t] = u;
  float ss = v.x * v.x + v.y * v.y + v.z * v.z + v.w * v.w;  // norms stay exact f32
  #pragma unroll
  for (int off = 32; off; off >>= 1) ss += __shfl_down(ss, off);
  __shared__ float red[4];
  if ((t & 63) == 0) red[t >> 6] = ss;
  __syncthreads();
  if (t == 0) (isB ? yy : xx)[row] = red[0] + red[1] + red[2] + red[3];
}

// ---------------- fused GEMM: R8 structure, fp8 dtype. 256x256 tile, BK=64, 2 buffers --
// 8 waves (2M x 4N), per-wave 128x64, 16x16x32_fp8_fp8 (K=32, i64 operands, f32x4 acc).
// 4 fine phases per K-tile (reads 12/4/8/0 x b64 + staging), lgkmcnt(0)+sched_barrier
// before each 16-MFMA cluster, vmcnt(0) at tile end (R8-proven). LDS buffers are 32KB
// each (fp8) -> 64KB total -> 2 blocks/CU (16 waves/CU TLP, m114 overlap).
// Swizzle: 64B rows, 16B chunks, chunk ^= (row>>1)&3 both-sides -> <=2-way (free).
// Products carry x256 (inputs x16); epilogue multiplies by exact 1/256.
__global__ __launch_bounds__(512, 2) void gemm_fused(
    const uint8_t* __restrict__ Afp, const uint8_t* __restrict__ Bfp,
    const float* __restrict__ xx, const float* __restrict__ yy,
    const float* __restrict__ p_log_tau, const float* __restrict__ p_margin,
    float* __restrict__ row_partial, float* __restrict__ accums) {
  __shared__ __align__(16) char lds[65536];   // 2 buffers x (A 16KB + B 16KB)

  const int tid = threadIdx.x;
  const int wave = tid >> 6, lane = tid & 63;
  const int l15 = lane & 15, g4 = lane >> 4;
  const int waveM = wave >> 2, waveN = wave & 3;        // 2 x 4
  const int bx = blockIdx.x, by = blockIdx.y;
  const int blockRow = by * 256, blockCol = bx * 256;

  // staging: per GLL 512 threads cover 128 rows x 64B; thread t -> row t>>2,
  // 16B-chunk (t&3) ^ ((row>>1)&3) (pre-swizzled source; LDS written linearly by HW)
  const int srow = tid >> 2;                            // 0..127
  const int schunk = (tid & 3) ^ ((srow >> 1) & 3);     // involution
  const uint8_t* aSrc = Afp + (size_t)(blockRow + srow) * DK + schunk * 16;
  const uint8_t* bSrc = Bfp + (size_t)(blockCol + srow) * DK + schunk * 16;
  const int ldst = wave * 1024;                         // wave-uniform base in 8KB call

#define GLL(gp, lp) __builtin_amdgcn_global_load_lds(                                   \
      (const __attribute__((address_space(1))) void*)(gp),                             \
      (__attribute__((address_space(3))) void*)(lp), 16, 0, 0)
#define STAGE_A(kt, cb) do { char* b_ = lds + (cb);                                     \
    const uint8_t* s_ = aSrc + (kt) * BKT;                                              \
    GLL(s_, b_ + ldst); GLL(s_ + 128 * DK, b_ + 8192 + ldst); } while (0)
#define STAGE_B(kt, cb) do { char* b_ = lds + (cb) + 16384;                             \
    const uint8_t* s_ = bSrc + (kt) * BKT;                                              \
    GLL(s_, b_ + ldst); GLL(s_ + 128 * DK, b_ + 8192 + ldst); } while (0)
#define RD64(off) (*(const long*)(lds + (off)))
#define BAR() do { __builtin_amdgcn_s_barrier(); asm volatile("" ::: "memory"); } while (0)
#define LGKM0() do { asm volatile("s_waitcnt lgkmcnt(0)" ::: "memory");                 \
                     __builtin_amdgcn_sched_barrier(0); } while (0)
#define MFMA8(a_, b_, c_) __builtin_amdgcn_mfma_f32_16x16x32_fp8_fp8((a_), (b_), (c_), 0, 0, 0)

  f32x4 acc[8][4];
  #pragma unroll
  for (int m = 0; m < 8; ++m)
    #pragma unroll
    for (int n = 0; n < 4; ++n)
      acc[m][n] = (f32x4){0.f, 0.f, 0.f, 0.f};

  // frag reads: 64B rows; lane reads 8B at K-offset kk*32 + g4*8, chunk XOR (row>>1)&3.
  // (row>>1)&3 == (l15>>1)&3 for all frag rows (row = base16*m + l15, base16%16==0).
  const int s2 = (l15 >> 1) & 3;
  const int co0 = (((g4 >> 1) ^ s2) << 4) + ((g4 & 1) << 3);          // kk=0
  const int co1 = ((((g4 >> 1) + 2) ^ s2) << 4) + ((g4 & 1) << 3);    // kk=1
  const int aRow = (waveM * 128 + l15) * 64;            // + m*1024
  const int bRow = 16384 + (waveN * 64 + l15) * 64;     // + n*1024

  long af[4][2], bf[4][2];

  // prologue: stage tile 0 into buffer 0, drain, barrier
  STAGE_A(0, 0); STAGE_B(0, 0);
  asm volatile("s_waitcnt vmcnt(0)" ::: "memory");
  BAR();

  for (int t = 0; t < NKT; ++t) {
    const int cb = (t & 1) * 32768;
    const int nb = ((t + 1) & 1) * 32768;
    // ---- phase 0: Q(m0-3 x n0-1); 12 reads; stage A(t+1) ----
    #pragma unroll
    for (int m = 0; m < 4; ++m) {
      af[m][0] = RD64(cb + aRow + m * 1024 + co0);
      af[m][1] = RD64(cb + aRow + m * 1024 + co1);
    }
    #pragma unroll
    for (int n = 0; n < 2; ++n) {
      bf[n][0] = RD64(cb + bRow + n * 1024 + co0);
      bf[n][1] = RD64(cb + bRow + n * 1024 + co1);
    }
    if (t + 1 < NKT) STAGE_A(t + 1, nb);
    BAR(); LGKM0();
    __builtin_amdgcn_s_setprio(1);
    #pragma unroll
    for (int m = 0; m < 4; ++m)
      #pragma unroll
      for (int n = 0; n < 2; ++n) {
        acc[m][n] = MFMA8(af[m][0], bf[n][0], acc[m][n]);
        acc[m][n] = MFMA8(af[m][1], bf[n][1], acc[m][n]);
      }
    __builtin_amdgcn_s_setprio(0);
    BAR();
    // ---- phase 1: Q(m0-3 x n2-3); 4 reads; stage B(t+1) ----
    #pragma unroll
    for (int n = 2; n < 4; ++n) {
      bf[n][0] = RD64(cb + bRow + n * 1024 + co0);
      bf[n][1] = RD64(cb + bRow + n * 1024 + co1);
    }
    if (t + 1 < NKT) STAGE_B(t + 1, nb);
    BAR(); LGKM0();
    __builtin_amdgcn_s_setprio(1);
    #pragma unroll
    for (int m = 0; m < 4; ++m)
      #pragma unroll
      for (int n = 2; n < 4; ++n) {
        acc[m][n] = MFMA8(af[m][0], bf[n][0], acc[m][n]);
        acc[m][n] = MFMA8(af[m][1], bf[n][1], acc[m][n]);
      }
    __builtin_amdgcn_s_setprio(0);
    BAR();
    // ---- phase 2: Q(m4-7 x n0-1); 8 reads (overwrite af) ----
    #pragma unroll
    for (int m = 0; m < 4; ++m) {
      af[m][0] = RD64(cb + aRow + (m + 4) * 1024 + co0);
      af[m][1] = RD64(cb + aRow + (m + 4) * 1024 + co1);
    }
    BAR(); LGKM0();
    __builtin_amdgcn_s_setprio(1);
    #pragma unroll
    for (int m = 0; m < 4; ++m)
      #pragma unroll
      for (int n = 0; n < 2; ++n) {
        acc[m + 4][n] = MFMA8(af[m][0], bf[n][0], acc[m + 4][n]);
        acc[m + 4][n] = MFMA8(af[m][1], bf[n][1], acc[m + 4][n]);
      }
    __builtin_amdgcn_s_setprio(0);
    BAR();
    // ---- phase 3: Q(m4-7 x n2-3); no reads; tile-end vmcnt drain ----
    __builtin_amdgcn_s_setprio(1);
    #pragma unroll
    for (int m = 0; m < 4; ++m)
      #pragma unroll
      for (int n = 2; n < 4; ++n) {
        acc[m + 4][n] = MFMA8(af[m][0], bf[n][0], acc[m + 4][n]);
        acc[m + 4][n] = MFMA8(af[m][1], bf[n][1], acc[m + 4][n]);
      }
    __builtin_amdgcn_s_setprio(0);
    asm volatile("s_waitcnt vmcnt(0)" ::: "memory");   // drains GLLs issued >=2 phases ago
    BAR();
  }
#undef STAGE_A
#undef STAGE_B
#undef GLL
#undef RD64
#undef BAR
#undef LGKM0
#undef MFMA8

  // ---- fused epilogue: poincare dist via log2, exp-sums, dist sums ----
  const float lt = *p_log_tau;
  const float mg = *p_margin;
  const float marg = fmaxf(mg, 0.f);
  const float tau = 1.99f / (1.f + __expf(-lt)) + 0.01f;
  const float nl = -LN2F / tau;            // exp(L2*nl) == exp(-dist/tau)
  const float em = __expf(-marg);          // diagonal exp correction factor
  const bool diagblk = (bx == by);
  const float inv256 = 0.00390625f;        // undo x16 * x16 input scaling (exact)

  float yyj[4], rcpy[4]; int gj[4];
  #pragma unroll
  for (int n = 0; n < 4; ++n) {
    gj[n] = blockCol + waveN * 64 + n * 16 + l15;        // C/D col = lane&15
    yyj[n] = yy[gj[n]];
    rcpy[n] = __builtin_amdgcn_rcpf(1.f - yyj[n]);
  }

  float dL = 0.f, dDiagL = 0.f;            // dist sums in log2 units
  float* rsum = (float*)lds;               // reuse LDS: [256 rows][4 waveN] partials

  #pragma unroll
  for (int m = 0; m < 8; ++m) {
    #pragma unroll
    for (int r = 0; r < 4; ++r) {
      const int gi = blockRow + waveM * 128 + m * 16 + g4 * 4 + r;  // C/D row
      const float xxi = xx[gi];
      const float p2 = 2.f * __builtin_amdgcn_rcpf(1.f - xxi);
      float e_acc = 0.f;
      #pragma unroll
      for (int n = 0; n < 4; ++n) {
        const float xy = acc[m][n][r] * inv256;
        const float sq = fmaxf(xxi + yyj[n] - 2.f * xy, 0.f);
        const float tt = sq * (p2 * rcpy[n]);            // arg = 1 + tt
        const float s = __builtin_amdgcn_sqrtf(tt * (tt + 2.f));
        const float w = tt + 1.f + s;                    // arg + sqrt(arg^2-1)
        const float L2 = __log2f(fmaxf(w, 1.f + EPSF));  // dist = L2 * ln2
        float e = __expf(L2 * nl);
        dL += L2;
        if (diagblk && gi == gj[n]) { dDiagL += L2; e *= em; }
        e_acc += e;
      }
      e_acc += __shfl_xor(e_acc, 1);
      e_acc += __shfl_xor(e_acc, 2);
      e_acc += __shfl_xor(e_acc, 4);
      e_acc += __shfl_xor(e_acc, 8);
      if (l15 == 0) {
        const int rloc = waveM * 128 + m * 16 + g4 * 4 + r;
        rsum[rloc * 4 + waveN] = e_acc;
      }
    }
  }

  // block-level scalar reductions -> 2 atomics per wave (log2 units)
  #pragma unroll
  for (int off = 32; off; off >>= 1) {
    dL += __shfl_down(dL, off);
    dDiagL += __shfl_down(dDiagL, off);
  }
  if (lane == 0) {
    atomicAdd(&accums[0], dL);
    if (diagblk) atomicAdd(&accums[1], dDiagL);
  }

  __syncthreads();
  if (tid < 256) {
    const float rs = rsum[tid * 4 + 0] + rsum[tid * 4 + 1] + rsum[tid * 4 + 2] + rsum[tid * 4 + 3];
    row_partial[(size_t)bx * BN + blockRow + tid] = rs;
  }
}

// ---------------- finalize: sum col-tile partials, log, final linear combo ----------------
__global__ __launch_bounds__(1024) void finalize_kernel(
    const float* __restrict__ row_partial, const float* __restrict__ accums,
    const float* __restrict__ p_log_tau, const float* __restrict__ p_margin,
    float* __restrict__ out) {
  const int t = threadIdx.x;
  float lsum = 0.f;
  for (int i = t; i < BN; i += 1024) {
    float s = 0.f;
    #pragma unroll
    for (int c = 0; c < 32; ++c) s += row_partial[(size_t)c * BN + i];
    lsum += __logf(s);
  }
  #pragma unroll
  for (int off = 32; off; off >>= 1) lsum += __shfl_down(lsum, off);
  __shared__ float red[16];
  if ((t & 63) == 0) red[t >> 6] = lsum;
  __syncthreads();
  if (t == 0) {
    float total = 0.f;
    #pragma unroll
    for (int w = 0; w < 16; ++w) total += red[w];
    const float lt = *p_log_tau;
    const float mg = *p_margin;
    const float marg = fmaxf(mg, 0.f);
    const float tau = 1.99f / (1.f + __expf(-lt)) + 0.01f;
    const float C = marg;
    const float d_tot = accums[0] * LN2F;
    const float d_diag = accums[1] * LN2F;
    const float bf = (float)BN;
    const float mean_lse = total / bf + C;
    const float sum_scores = -d_tot / tau + marg * (bf * bf - bf);  // margin closed-form
    const float sum_diag_scores = -d_diag / tau;
    const float loss = mean_lse
                     - (1.f - LSMOOTH) * (sum_diag_scores / bf)
                     - LSMOOTH * (sum_scores / (bf * bf));
    out[0] = loss;
    out[1] = d_diag / bf;   // pos_dist
    out[2] = tau;
    out[3] = mg;            // maximum(margin, margin) == margin
  }
}

extern "C" void kernel_launch(void* const* d_in, const int* in_sizes, int n_in,
                              void* d_out, int out_size, void* d_ws, size_t ws_size,
                              hipStream_t stream) {
  const float* sign = (const float*)d_in[0];
  const float* text = (const float*)d_in[1];
  const float* p_log_tau = (const float*)d_in[2];
  const float* p_margin = (const float*)d_in[3];
  float* out = (float*)d_out;

  char* ws = (char*)d_ws;
  uint8_t* Afp = (uint8_t*)ws;                                       // 8 MiB
  uint8_t* Bfp = (uint8_t*)(ws + (size_t)BN * DK);                   // 8 MiB
  float* xx = (float*)(ws + (size_t)BN * DK * 2);
  float* yy = xx + BN;
  float* row_partial = yy + BN;                                      // 32 x 8192 floats
  float* accums = row_partial + 32 * BN;                             // 2 floats

  (void)hipMemsetAsync(accums, 0, 2 * sizeof(float), stream);
  prep_kernel<<<dim3(2 * BN), 256, 0, stream>>>(sign, text, (uint32_t*)Afp, (uint32_t*)Bfp, xx, yy);
  gemm_fused<<<dim3(BN / 256, BN / 256), 512, 0, stream>>>(
      Afp, Bfp, xx, yy, p_log_tau, p_margin, row_partial, accums);
  finalize_kernel<<<1, 1024, 0, stream>>>(row_partial, accums, p_log_tau, p_margin, out);
}